// Round 6
// baseline (306.392 us; speedup 1.0000x reference)
//
#include <hip/hip_runtime.h>
#include <hip/hip_bf16.h>

// Fused quantized conv chain, integer-scaled domain (bit-exact vs reference):
//   X = 128*fake_quant(x), Y = clamp(floor(128*b1q+0.5 + sum X*w1q),-128,127),
//   Z = clamp(floor(128*b2q+0.5 + sum Y*w2q),-128,127), out = Z/128.
//
// Round-6 structure: each thread processes 8 chunks of 8 positions, chunks
// strided 2048 apart (wave-contiguous within each step). ALL loads for chunk
// j+1 (main float4 x2 + halo float2 x2, per channel) are issued during the
// conv compute of chunk j (~3400 cycles of cover). 512 blocks = 2/CU exactly.

#define T 8        // positions per chunk
#define CHUNKS 8   // chunks per thread

__device__ __forceinline__ float q128(float v) {
    float t = floorf(fmaf(v, 128.0f, 0.5f));
    return fminf(fmaxf(t, -128.0f), 127.0f);   // v_floor + v_med3
}

__device__ __forceinline__ float fq8(float v) { return q128(v) * 0.0078125f; }

// Issue all loads for chunk JJ into buffer (JJ&1). JJ is a literal in the
// unrolled loop, so all array indices constant-fold (no scratch spill).
#define ISSUE_CHUNK(JJ)                                                    \
    {                                                                      \
        const int  bb    = (JJ) & 1;                                       \
        const int  pp    = blockBase + ((JJ) * 256 + t) * T;               \
        const float* basep = x + rowBase + (unsigned)pp;                   \
        const bool pll = (pp == 0);                                        \
        const bool prr = (pp + T == L);                                    \
        _Pragma("unroll")                                                  \
        for (int i = 0; i < 4; ++i) {                                      \
            const float* bi = basep + (unsigned)i * (unsigned)L;           \
            m[bb][i][0] = *(const float4*)(bi);                            \
            m[bb][i][1] = *(const float4*)(bi + 4);                        \
            hl[bb][i]   = *(const float2*)(pll ? bi : bi - 2);             \
            hr[bb][i]   = *(const float2*)(prr ? bi : bi + T);             \
        }                                                                  \
    }

__global__ __launch_bounds__(256, 2) void fused_qconv_kernel(
    const float* __restrict__ x,
    const float* __restrict__ w1, const float* __restrict__ b1,
    const float* __restrict__ gamma, const float* __restrict__ beta,
    const float* __restrict__ bn_mean, const float* __restrict__ bn_var,
    const float* __restrict__ w2, const float* __restrict__ b2,
    float* __restrict__ out,
    int L)
{
    // ---- per-channel weight row: [0..11]=w1q, [12]=128*b1q+0.5,
    //      [13..15]=w2q[0][c][k], [16..18]=w2q[1][c][k], [19]=pad ----
    __shared__ float s_cw[8][20];
    __shared__ float s_b2[2];

    const int t = threadIdx.x;
    if (t < 162) {
        if (t < 160) {
            const int c = t / 20, j = t - c * 20;
            float v;
            if (j < 12) {
                float sf = gamma[c] * (1.0f / sqrtf(bn_var[c] + 1e-5f));
                v = fq8(w1[c * 12 + j] * sf);
            } else if (j == 12) {
                float sf = gamma[c] * (1.0f / sqrtf(bn_var[c] + 1e-5f));
                v = fmaf(fq8((b1[c] - bn_mean[c]) * sf + beta[c]), 128.0f, 0.5f);
            } else if (j < 16) {
                v = fq8(w2[c * 3 + (j - 13)]);          // o=0
            } else if (j < 19) {
                v = fq8(w2[24 + c * 3 + (j - 16)]);     // o=1
            } else {
                v = 0.0f;
            }
            s_cw[c][j] = v;
        } else {
            s_b2[t - 160] = fmaf(fq8(b2[t - 160]), 128.0f, 0.5f);
        }
    }
    __syncthreads();

    const int n = blockIdx.y;
    const int blockBase = blockIdx.x * (256 * CHUNKS * T);   // 16384 positions/block
    const unsigned rowBase = (unsigned)(n * 4) * (unsigned)L;

    // double-buffered raw loads for the pipelined chunk stream
    float4 m[2][4][2];
    float2 hl[2][4], hr[2][4];

    // prologue: issue chunk 0
    ISSUE_CHUNK(0);

#pragma unroll
    for (int j = 0; j < CHUNKS; ++j) {
        const int  b  = j & 1;
        const int  p  = blockBase + (j * 256 + t) * T;
        const bool pl = (p == 0);
        const bool pr = (p + T == L);

        // ---- quantize chunk j's window (consumes buffer b) ----
        float X[4][12];
#pragma unroll
        for (int i = 0; i < 4; ++i) {
            X[i][2] = q128(m[b][i][0].x); X[i][3] = q128(m[b][i][0].y);
            X[i][4] = q128(m[b][i][0].z); X[i][5] = q128(m[b][i][0].w);
            X[i][6] = q128(m[b][i][1].x); X[i][7] = q128(m[b][i][1].y);
            X[i][8] = q128(m[b][i][1].z); X[i][9] = q128(m[b][i][1].w);
            X[i][0]  = pl ? 0.0f : q128(hl[b][i].x);
            X[i][1]  = pl ? 0.0f : q128(hl[b][i].y);
            X[i][10] = pr ? 0.0f : q128(hr[b][i].x);
            X[i][11] = pr ? 0.0f : q128(hr[b][i].y);
        }

        // ---- issue ALL loads for chunk j+1 (hidden under conv below) ----
        if (j + 1 < CHUNKS) ISSUE_CHUNK(j + 1);

        // ---- conv chain in scaled-integer domain ----
        float acc[2][T];
        {
            const float a0 = s_b2[0], a1 = s_b2[1];
#pragma unroll
            for (int q = 0; q < T; ++q) { acc[0][q] = a0; acc[1][q] = a1; }
        }

#pragma unroll
        for (int c = 0; c < 8; ++c) {
            const float4 cw0 = *(const float4*)&s_cw[c][0];
            const float4 cw1 = *(const float4*)&s_cw[c][4];
            const float4 cw2 = *(const float4*)&s_cw[c][8];
            const float4 cw3 = *(const float4*)&s_cw[c][12];
            const float4 cw4 = *(const float4*)&s_cw[c][16];
            const float w00 = cw0.x, w01 = cw0.y, w02 = cw0.z;
            const float w10 = cw0.w, w11 = cw1.x, w12 = cw1.y;
            const float w20 = cw1.z, w21 = cw1.w, w22 = cw2.x;
            const float w30 = cw2.y, w31 = cw2.z, w32 = cw2.w;
            const float bc  = cw3.x;                        // 128*b1q + 0.5
            const float u0 = cw3.y, u1 = cw3.z, u2 = cw3.w; // w2q[0][c][:]
            const float v0 = cw4.x, v1 = cw4.y, v2 = cw4.z; // w2q[1][c][:]

#pragma unroll
            for (int pp = 0; pp < T + 2; ++pp) {
                float v = bc;
                v = fmaf(X[0][pp], w00, v); v = fmaf(X[0][pp+1], w01, v); v = fmaf(X[0][pp+2], w02, v);
                v = fmaf(X[1][pp], w10, v); v = fmaf(X[1][pp+1], w11, v); v = fmaf(X[1][pp+2], w12, v);
                v = fmaf(X[2][pp], w20, v); v = fmaf(X[2][pp+1], w21, v); v = fmaf(X[2][pp+2], w22, v);
                v = fmaf(X[3][pp], w30, v); v = fmaf(X[3][pp+1], w31, v); v = fmaf(X[3][pp+2], w32, v);
                float Y = fminf(fmaxf(floorf(v), -128.0f), 127.0f);   // 128*y_q
                if (pp == 0     && pl) Y = 0.0f;   // y[-1] is conv2 padding zero
                if (pp == T + 1 && pr) Y = 0.0f;   // y[L] is conv2 padding zero
                if (pp < T) {
                    acc[0][pp] = fmaf(Y, u0, acc[0][pp]);
                    acc[1][pp] = fmaf(Y, v0, acc[1][pp]);
                }
                if (pp >= 1 && pp - 1 < T) {
                    acc[0][pp-1] = fmaf(Y, u1, acc[0][pp-1]);
                    acc[1][pp-1] = fmaf(Y, v1, acc[1][pp-1]);
                }
                if (pp >= 2) {
                    acc[0][pp-2] = fmaf(Y, u2, acc[0][pp-2]);
                    acc[1][pp-2] = fmaf(Y, v2, acc[1][pp-2]);
                }
            }
        }

        // ---- final quantize + store (lane-contiguous within the wave) ----
        float* ob = out + (unsigned)(n * 2) * (unsigned)L + (unsigned)p;
#pragma unroll
        for (int o = 0; o < 2; ++o) {
            float4 r0, r1;
            r0.x = fminf(fmaxf(floorf(acc[o][0]), -128.0f), 127.0f) * 0.0078125f;
            r0.y = fminf(fmaxf(floorf(acc[o][1]), -128.0f), 127.0f) * 0.0078125f;
            r0.z = fminf(fmaxf(floorf(acc[o][2]), -128.0f), 127.0f) * 0.0078125f;
            r0.w = fminf(fmaxf(floorf(acc[o][3]), -128.0f), 127.0f) * 0.0078125f;
            r1.x = fminf(fmaxf(floorf(acc[o][4]), -128.0f), 127.0f) * 0.0078125f;
            r1.y = fminf(fmaxf(floorf(acc[o][5]), -128.0f), 127.0f) * 0.0078125f;
            r1.z = fminf(fmaxf(floorf(acc[o][6]), -128.0f), 127.0f) * 0.0078125f;
            r1.w = fminf(fmaxf(floorf(acc[o][7]), -128.0f), 127.0f) * 0.0078125f;
            *(float4*)(ob + (unsigned)o * (unsigned)L)     = r0;
            *(float4*)(ob + (unsigned)o * (unsigned)L + 4) = r1;
        }
    }
}

extern "C" void kernel_launch(void* const* d_in, const int* in_sizes, int n_in,
                              void* d_out, int out_size, void* d_ws, size_t ws_size,
                              hipStream_t stream) {
    const float* x       = (const float*)d_in[0];
    const float* w1      = (const float*)d_in[1];
    const float* b1      = (const float*)d_in[2];
    const float* gamma   = (const float*)d_in[3];
    const float* beta    = (const float*)d_in[4];
    const float* bn_mean = (const float*)d_in[5];
    const float* bn_var  = (const float*)d_in[6];
    const float* w2      = (const float*)d_in[7];
    const float* b2      = (const float*)d_in[8];
    float* out = (float*)d_out;

    const int B = 16;
    const int L = in_sizes[0] / (B * 4);             // 524288
    const int gridX = L / (256 * CHUNKS * T);        // 32 blocks per row
    const int gridY = B;                             // one row per blockIdx.y

    fused_qconv_kernel<<<dim3(gridX, gridY), 256, 0, stream>>>(
        x, w1, b1, gamma, beta, bn_mean, bn_var, w2, b2, out, L);
}

// Round 7
// 289.677 us; speedup vs baseline: 1.0577x; 1.0577x over previous
//
#include <hip/hip_runtime.h>

// Fused quantized conv chain, integer-scaled domain (bit-exact vs reference):
//   X = 128*fake_quant(x), Y = clamp(floor(128*b1q+0.5 + sum X*w1q),-128,127),
//   Z = clamp(floor(128*b2q+0.5 + sum Y*w2q),-128,127), out = Z/128.
//
// Round-7 structure: two kernels.
//  - prep_weights (1 block): computes the 162 quantized/folded weight floats
//    into d_ws (recomputed every call; d_ws is re-poisoned by the harness).
//  - fused_qconv_kernel: pure streaming compute. Weights are read with
//    UNIFORM addresses -> compiler emits scalar loads into SGPRs; the inner
//    conv is v_fma_f32 v,s,v,v. No LDS, no __syncthreads, no launch preamble.
//    __launch_bounds__(256,8) forces VGPR<=64 -> up to 8 waves/SIMD.

#define T 8  // output positions per thread

__device__ __forceinline__ float q128(float v) {
    float t = floorf(fmaf(v, 128.0f, 0.5f));
    return fminf(fmaxf(t, -128.0f), 127.0f);   // v_floor + v_med3
}

__device__ __forceinline__ float fq8(float v) { return q128(v) * 0.0078125f; }

// ws layout (floats): for c in 0..7 at ws[c*20 + j]:
//   j=0..11 : w1q[c][i][k] (BN-folded, fake-quantized)
//   j=12    : 128*b1q[c] + 0.5
//   j=13..15: w2q[0][c][k]
//   j=16..18: w2q[1][c][k]
//   j=19    : pad
// ws[160], ws[161]: 128*b2q[o] + 0.5
__global__ void prep_weights(
    const float* __restrict__ w1, const float* __restrict__ b1,
    const float* __restrict__ gamma, const float* __restrict__ beta,
    const float* __restrict__ bn_mean, const float* __restrict__ bn_var,
    const float* __restrict__ w2, const float* __restrict__ b2,
    float* __restrict__ ws)
{
    const int t = threadIdx.x;
    if (t < 160) {
        const int c = t / 20, j = t - c * 20;
        float v;
        if (j < 12) {
            float sf = gamma[c] * (1.0f / sqrtf(bn_var[c] + 1e-5f));
            v = fq8(w1[c * 12 + j] * sf);
        } else if (j == 12) {
            float sf = gamma[c] * (1.0f / sqrtf(bn_var[c] + 1e-5f));
            v = fmaf(fq8((b1[c] - bn_mean[c]) * sf + beta[c]), 128.0f, 0.5f);
        } else if (j < 16) {
            v = fq8(w2[c * 3 + (j - 13)]);          // o=0
        } else if (j < 19) {
            v = fq8(w2[24 + c * 3 + (j - 16)]);     // o=1
        } else {
            v = 0.0f;
        }
        ws[t] = v;
    } else if (t < 162) {
        ws[t] = fmaf(fq8(b2[t - 160]), 128.0f, 0.5f);
    }
}

__global__ __launch_bounds__(256, 8) void fused_qconv_kernel(
    const float* __restrict__ x,
    const float* __restrict__ wsu,
    float* __restrict__ out,
    int L)
{
    const int t = threadIdx.x;
    const int pc   = blockIdx.x * 256 + t;     // [0, L/T)
    const int pos0 = pc * T;
    const int n    = blockIdx.y;
    const bool le = (pos0 == 0);
    const bool re = (pos0 + T == L);

    // ---- load + quantize x window: positions pos0-2 .. pos0+9 ----
    float X[4][12];
    const float* xb = x + (unsigned)(n * 4) * (unsigned)L + (unsigned)pos0;
#pragma unroll
    for (int i = 0; i < 4; ++i) {
        const float* xr = xb + (unsigned)(i * L);
        float4 a = *(const float4*)(xr);                    // pos0..pos0+3
        float4 b = *(const float4*)(xr + 4);                // pos0+4..pos0+7
        float2 hl = *(const float2*)(le ? xr : xr - 2);     // pos0-2, pos0-1
        float2 hr = *(const float2*)(re ? xr : xr + T);     // pos0+8, pos0+9
        X[i][2] = q128(a.x); X[i][3] = q128(a.y); X[i][4] = q128(a.z); X[i][5] = q128(a.w);
        X[i][6] = q128(b.x); X[i][7] = q128(b.y); X[i][8] = q128(b.z); X[i][9] = q128(b.w);
        X[i][0]  = le ? 0.0f : q128(hl.x);
        X[i][1]  = le ? 0.0f : q128(hl.y);
        X[i][10] = re ? 0.0f : q128(hr.x);
        X[i][11] = re ? 0.0f : q128(hr.y);
    }

    // ---- conv2 accumulators (scaled domain): init = 128*b2q + 0.5 ----
    float acc[2][T];
    {
        const float a0 = wsu[160], a1 = wsu[161];   // uniform -> SGPR
#pragma unroll
        for (int q = 0; q < T; ++q) { acc[0][q] = a0; acc[1][q] = a1; }
    }

    // ---- conv chain; weights are uniform scalar loads (SGPRs) ----
#pragma unroll
    for (int c = 0; c < 8; ++c) {
        const float* wc = wsu + c * 20;
        const float w00 = wc[0], w01 = wc[1],  w02 = wc[2];
        const float w10 = wc[3], w11 = wc[4],  w12 = wc[5];
        const float w20 = wc[6], w21 = wc[7],  w22 = wc[8];
        const float w30 = wc[9], w31 = wc[10], w32 = wc[11];
        const float bc  = wc[12];                          // 128*b1q + 0.5
        const float u0 = wc[13], u1 = wc[14], u2 = wc[15]; // w2q[0][c][:]
        const float v0 = wc[16], v1 = wc[17], v2 = wc[18]; // w2q[1][c][:]

        // y positions l' = pos0-1+p, p in [0, 10)
#pragma unroll
        for (int p = 0; p < T + 2; ++p) {
            float v = bc;
            v = fmaf(X[0][p], w00, v); v = fmaf(X[0][p+1], w01, v); v = fmaf(X[0][p+2], w02, v);
            v = fmaf(X[1][p], w10, v); v = fmaf(X[1][p+1], w11, v); v = fmaf(X[1][p+2], w12, v);
            v = fmaf(X[2][p], w20, v); v = fmaf(X[2][p+1], w21, v); v = fmaf(X[2][p+2], w22, v);
            v = fmaf(X[3][p], w30, v); v = fmaf(X[3][p+1], w31, v); v = fmaf(X[3][p+2], w32, v);
            float Y = fminf(fmaxf(floorf(v), -128.0f), 127.0f);   // 128*y_q
            if (p == 0     && le) Y = 0.0f;   // y[-1] is conv2 padding zero
            if (p == T + 1 && re) Y = 0.0f;   // y[L] is conv2 padding zero
            if (p < T) {
                acc[0][p] = fmaf(Y, u0, acc[0][p]);
                acc[1][p] = fmaf(Y, v0, acc[1][p]);
            }
            if (p >= 1 && p - 1 < T) {
                acc[0][p-1] = fmaf(Y, u1, acc[0][p-1]);
                acc[1][p-1] = fmaf(Y, v1, acc[1][p-1]);
            }
            if (p >= 2) {
                acc[0][p-2] = fmaf(Y, u2, acc[0][p-2]);
                acc[1][p-2] = fmaf(Y, v2, acc[1][p-2]);
            }
        }
    }

    // ---- final quantize + scale-back + vectorized store ----
    float* ob = out + (unsigned)(n * 2) * (unsigned)L + (unsigned)pos0;
#pragma unroll
    for (int o = 0; o < 2; ++o) {
        float4 r0, r1;
        r0.x = fminf(fmaxf(floorf(acc[o][0]), -128.0f), 127.0f) * 0.0078125f;
        r0.y = fminf(fmaxf(floorf(acc[o][1]), -128.0f), 127.0f) * 0.0078125f;
        r0.z = fminf(fmaxf(floorf(acc[o][2]), -128.0f), 127.0f) * 0.0078125f;
        r0.w = fminf(fmaxf(floorf(acc[o][3]), -128.0f), 127.0f) * 0.0078125f;
        r1.x = fminf(fmaxf(floorf(acc[o][4]), -128.0f), 127.0f) * 0.0078125f;
        r1.y = fminf(fmaxf(floorf(acc[o][5]), -128.0f), 127.0f) * 0.0078125f;
        r1.z = fminf(fmaxf(floorf(acc[o][6]), -128.0f), 127.0f) * 0.0078125f;
        r1.w = fminf(fmaxf(floorf(acc[o][7]), -128.0f), 127.0f) * 0.0078125f;
        *(float4*)(ob + (unsigned)o * (unsigned)L)     = r0;
        *(float4*)(ob + (unsigned)o * (unsigned)L + 4) = r1;
    }
}

extern "C" void kernel_launch(void* const* d_in, const int* in_sizes, int n_in,
                              void* d_out, int out_size, void* d_ws, size_t ws_size,
                              hipStream_t stream) {
    const float* x       = (const float*)d_in[0];
    const float* w1      = (const float*)d_in[1];
    const float* b1      = (const float*)d_in[2];
    const float* gamma   = (const float*)d_in[3];
    const float* beta    = (const float*)d_in[4];
    const float* bn_mean = (const float*)d_in[5];
    const float* bn_var  = (const float*)d_in[6];
    const float* w2      = (const float*)d_in[7];
    const float* b2      = (const float*)d_in[8];
    float* out = (float*)d_out;
    float* ws  = (float*)d_ws;

    const int B = 16;
    const int L = in_sizes[0] / (B * 4);        // 524288
    const int gridX = (L / T) / 256;            // 256
    const int gridY = B;

    prep_weights<<<1, 256, 0, stream>>>(w1, b1, gamma, beta, bn_mean, bn_var,
                                        w2, b2, ws);
    fused_qconv_kernel<<<dim3(gridX, gridY), 256, 0, stream>>>(x, ws, out, L);
}